// Round 6
// baseline (2759.050 us; speedup 1.0000x reference)
//
#include <hip/hip_runtime.h>
#include <math.h>
#include <stdint.h>

#define HIDDEN 4096
#define NEXP   64
#define TOKS   64                // tokens per workgroup
#define NWV    16
#define KPW    (HIDDEN / NWV)    // 256: K-slice per wave
#define KC     16                // k floats per staged chunk
#define NCH    (KPW / KC)        // 16 chunks
#define XW_FL  (TOKS * KC)       // 1024 floats per tile (X or W)
#define WV_FL  (2 * XW_FL)       // 2048 floats per wave (X|W, single-buffered)

// async global->LDS, 16B/lane, linear dest (wave-uniform base + lane*16)
__device__ __forceinline__ void gload_lds16(const float* g, float* l) {
    __builtin_amdgcn_global_load_lds(
        (const __attribute__((address_space(1))) void*)g,
        (__attribute__((address_space(3))) void*)l, 16, 0, 0);
}

// Fused MoE router: fp32 register-tiled GEMM (no fp32 MFMA on CDNA4) + top-2.
// R5 post-mortem: 2 waves/SIMD left VALU 35% busy (stall-bound). R6: 16 waves
// (4/SIMD) for TLP; per-wave private K-slice 256, KC=16, SINGLE-buffered LDS
// (8KB/wave x16 = 128KB). Per-wave flow: vmcnt(0) -> 64 ds_read_b128 + 1024
// FMA -> lgkmcnt(0) -> issue next 8 global_load_lds. No main-loop barriers.
// Source-swizzle chunk^=(row>>3)&3 (rule #21) => all tile reads <=2-way (free).
// 4-round LDS tree combines 16 K-partials; R2/R5-verified top-2 epilogue.
__global__ __launch_bounds__(1024, 4) void router_kernel(
    const float* __restrict__ X,
    const float* __restrict__ W,
    const float* __restrict__ Bv,
    float* __restrict__ out, int nTok)
{
    __shared__ float smem[NWV * WV_FL];   // 131072 B; reused by reduction tiles

    const int tid = threadIdx.x;
    const int wv  = __builtin_amdgcn_readfirstlane(tid >> 6);
    const int l   = tid & 63;
    const int tr  = l >> 3;          // token-group: rows 8tr..8tr+7
    const int ec  = l & 7;           // expert-group: cols 8ec..8ec+7
    const int t0  = blockIdx.x * TOKS;
    const int kb  = wv * KPW;

    // staging: 4 instrs per tile; instr r covers rows 16r..16r+15, lane l ->
    // row 16r+(l>>2), 16B granule (l&3). Global source pre-swizzled by
    // (row>>3)&3 so the linear LDS dest is read-conflict-light (R5-verified).
    const int srow = l >> 2;
    const int schk = l & 3;
    const float* Xg[4]; const float* Wg[4];
#pragma unroll
    for (int r = 0; r < 4; ++r) {
        const int row  = 16 * r + srow;
        const int koff = ((schk ^ ((row >> 3) & 3)) << 2);
        Xg[r] = X + (size_t)(t0 + row) * HIDDEN + kb + koff;
        Wg[r] = W + (size_t)row * HIDDEN + kb + koff;
    }
    float* wb = smem + wv * WV_FL;   // [X 1024 fl | W 1024 fl]

    float acc[8][8];
#pragma unroll
    for (int i = 0; i < 8; ++i)
#pragma unroll
        for (int j = 0; j < 8; ++j) acc[i][j] = 0.0f;

    const int mtr = (tr & 3) << 2;   // X read swizzle offset (lane-const)
    const int mec = (ec & 3) << 2;   // W read swizzle offset (lane-const)

    // prologue: stage chunk 0
#pragma unroll
    for (int r = 0; r < 4; ++r) gload_lds16(Xg[r], wb + r * 256);
#pragma unroll
    for (int r = 0; r < 4; ++r) gload_lds16(Wg[r], wb + XW_FL + r * 256);

#pragma unroll 1
    for (int c = 0; c < NCH; ++c) {
        asm volatile("s_waitcnt vmcnt(0)" ::: "memory");   // my 8 loads landed
        const float* xl = wb;
        const float* wl = wb + XW_FL;
#pragma unroll
        for (int kg = 0; kg < 4; ++kg) {
            const int kxo = (kg << 2) ^ mtr;
            const int kwo = (kg << 2) ^ mec;
            float4 xfv[8];
#pragma unroll
            for (int i = 0; i < 8; ++i)
                xfv[i] = *(const float4*)(xl + (8 * tr + i) * KC + kxo);
#pragma unroll
            for (int j = 0; j < 8; ++j) {
                const float4 wf = *(const float4*)(wl + (8 * ec + j) * KC + kwo);
#pragma unroll
                for (int i = 0; i < 8; ++i) {
                    acc[i][j] = fmaf(xfv[i].x, wf.x, acc[i][j]);
                    acc[i][j] = fmaf(xfv[i].y, wf.y, acc[i][j]);
                    acc[i][j] = fmaf(xfv[i].z, wf.z, acc[i][j]);
                    acc[i][j] = fmaf(xfv[i].w, wf.w, acc[i][j]);
                }
            }
        }
        asm volatile("s_waitcnt lgkmcnt(0)" ::: "memory");  // LDS reads retired
        if (c + 1 < NCH) {           // WAR-safe: reads done; issue next chunk
            const int ko = (c + 1) * KC;
#pragma unroll
            for (int r = 0; r < 4; ++r) gload_lds16(Xg[r] + ko, wb + r * 256);
#pragma unroll
            for (int r = 0; r < 4; ++r) gload_lds16(Wg[r] + ko, wb + XW_FL + r * 256);
        }
    }

    // ---- cross-wave K-reduction: 4 rounds of pairwise LDS adds.
    // Tile t at smem+t*4096 (16KB); granule index (2ec+g)^tr spreads banks.
    __syncthreads();
#pragma unroll
    for (int half = 8; half >= 1; half >>= 1) {
        if (wv >= half && wv < 2 * half) {
            float* tb = &smem[(wv - half) * 4096];
#pragma unroll
            for (int i = 0; i < 8; ++i) {
                const int base = (8 * tr + i) * 64;
                *(float4*)&tb[base + (((2 * ec + 0) ^ tr) << 2)] =
                    make_float4(acc[i][0], acc[i][1], acc[i][2], acc[i][3]);
                *(float4*)&tb[base + (((2 * ec + 1) ^ tr) << 2)] =
                    make_float4(acc[i][4], acc[i][5], acc[i][6], acc[i][7]);
            }
        }
        __syncthreads();
        if (wv < half) {
            float* tb = &smem[wv * 4096];
#pragma unroll
            for (int i = 0; i < 8; ++i) {
                const int base = (8 * tr + i) * 64;
                const float4 a = *(const float4*)&tb[base + (((2 * ec + 0) ^ tr) << 2)];
                const float4 b = *(const float4*)&tb[base + (((2 * ec + 1) ^ tr) << 2)];
                acc[i][0] += a.x; acc[i][1] += a.y; acc[i][2] += a.z; acc[i][3] += a.w;
                acc[i][4] += b.x; acc[i][5] += b.y; acc[i][6] += b.z; acc[i][7] += b.w;
            }
        }
        __syncthreads();
    }

    // ---- epilogue: wave 0 holds the final 64x64 tile (R2/R5-verified) ----
    if (wv == 0) {
        const size_t offSel = (size_t)nTok * 2;
        const size_t offLog = (size_t)nTok * 4;

        const float4 b0 = *(const float4*)(Bv + 8 * ec);
        const float4 b1 = *(const float4*)(Bv + 8 * ec + 4);
#pragma unroll
        for (int i = 0; i < 8; ++i) {
            acc[i][0] += b0.x; acc[i][1] += b0.y; acc[i][2] += b0.z; acc[i][3] += b0.w;
            acc[i][4] += b1.x; acc[i][5] += b1.y; acc[i][6] += b1.z; acc[i][7] += b1.w;
        }
        // router_logits: 8 ec-lanes cover a 256B row, float4 stores
#pragma unroll
        for (int i = 0; i < 8; ++i) {
            float* dst = out + offLog + (size_t)(t0 + 8 * tr + i) * NEXP + 8 * ec;
            *(float4*)dst       = make_float4(acc[i][0], acc[i][1], acc[i][2], acc[i][3]);
            *(float4*)(dst + 4) = make_float4(acc[i][4], acc[i][5], acc[i][6], acc[i][7]);
        }
        // top-2: per-lane scan of 8 experts, 3-step shfl_xor merge across the
        // 8 ec-lanes. Strict > + lowest-index tie-break (jax top_k semantics).
#pragma unroll
        for (int i = 0; i < 8; ++i) {
            float m1 = acc[i][0]; int i1 = 8 * ec;
            float m2 = -INFINITY; int i2 = 0;
#pragma unroll
            for (int j = 1; j < 8; ++j) {
                const float v = acc[i][j]; const int e = 8 * ec + j;
                if (v > m1)      { m2 = m1; i2 = i1; m1 = v; i1 = e; }
                else if (v > m2) { m2 = v; i2 = e; }
            }
#pragma unroll
            for (int m = 1; m < 8; m <<= 1) {
                const float om1 = __shfl_xor(m1, m);
                const int   oi1 = __shfl_xor(i1, m);
                const float om2 = __shfl_xor(m2, m);
                const int   oi2 = __shfl_xor(i2, m);
                const bool b1 = (om1 > m1) || (om1 == m1 && oi1 < i1);
                const float n1  = b1 ? om1 : m1; const int ni1 = b1 ? oi1 : i1;
                const float c2v = b1 ? m1 : om1; const int c2i = b1 ? i1 : oi1;
                const float c3v = b1 ? om2 : m2; const int c3i = b1 ? oi2 : i2;
                const bool b2 = (c3v > c2v) || (c3v == c2v && c3i < c2i);
                m1 = n1; i1 = ni1;
                m2 = b2 ? c3v : c2v; i2 = b2 ? c3i : c2i;
            }
            if (ec == 0) {
                const float ex  = expf(m2 - m1);
                const float inv = 1.0f / (1.0f + ex);
                const int t = t0 + 8 * tr + i;
                *(float2*)(out + (size_t)t * 2)          = make_float2(inv, ex * inv);
                *(float2*)(out + offSel + (size_t)t * 2) = make_float2((float)i1, (float)i2);
            }
        }
        if (blockIdx.x == 0 && tid == 0)
            out[offLog + (size_t)nTok * NEXP] = 0.0f;   // aux_loss
    }
}

extern "C" void kernel_launch(void* const* d_in, const int* in_sizes, int n_in,
                              void* d_out, int out_size, void* d_ws, size_t ws_size,
                              hipStream_t stream)
{
    const float* X  = (const float*)d_in[0];
    const float* W  = (const float*)d_in[1];
    const float* Bv = (const float*)d_in[2];
    float* out = (float*)d_out;
    const int nTok   = in_sizes[0] / HIDDEN;   // 16384
    const int blocks = nTok / TOKS;            // 256
    router_kernel<<<blocks, 1024, 0, stream>>>(X, W, Bv, out, nTok);
}

// Round 7
// 923.289 us; speedup vs baseline: 2.9883x; 2.9883x over previous
//
#include <hip/hip_runtime.h>
#include <math.h>
#include <stdint.h>

#define HIDDEN 4096
#define NEXP   64
#define TOKS   64                // tokens per workgroup
#define NWV    8
#define KBLK   2048              // K per block (split-K: 2 blocks per token tile)
#define KPW    (KBLK / NWV)      // 256: K-slice per wave
#define KC     16                // k floats per staged chunk
#define NCH    (KPW / KC)        // 16 chunks
#define XW_FL  (TOKS * KC)       // 1024 floats per tile (X or W)
#define WV_FL  (2 * XW_FL)       // 2048 floats per wave (X|W, single-buffered)

// async global->LDS, 16B/lane, linear dest (wave-uniform base + lane*16)
__device__ __forceinline__ void gload_lds16(const float* g, float* l) {
    __builtin_amdgcn_global_load_lds(
        (const __attribute__((address_space(1))) void*)g,
        (__attribute__((address_space(3))) void*)l, 16, 0, 0);
}

// Split-K fp32 register-tiled GEMM half: one block computes a 64-token x
// 64-expert PARTIAL over K=2048. 512 thr / 8 waves; per-wave private K-slice
// 256, KC=16, single-buffered 8KB LDS -> block LDS 64KB => 2 blocks/CU =
// 4 waves/SIMD (R5 was stall-bound at 2/SIMD, VALUBusy 35%). launch_bounds
// (512,2): observed semantics arg2=blocks/CU -> VGPR cap 128 (R5-verified;
// (1024,4) gave cap 64 and spilled 5.5GB in R6). Source-swizzle
// chunk^=(row>>3)&3 (rule #21) => tile reads <=2-way (free). 3-round LDS
// tree combines 8 K-partials; wave 0 stores the raw partial (no bias).
__global__ __launch_bounds__(512, 2) void gemm_half_kernel(
    const float* __restrict__ X,
    const float* __restrict__ W,
    float* __restrict__ outLog,   // final logits region (half 0 partial dest)
    float* __restrict__ wsP,      // workspace partial (half 1 dest)
    int nTok)
{
    __shared__ float smem[NWV * WV_FL];   // 65536 B; reused by reduction tiles

    const int tid = threadIdx.x;
    const int wv  = __builtin_amdgcn_readfirstlane(tid >> 6);
    const int l   = tid & 63;
    const int tr  = l >> 3;          // token-group: rows 8tr..8tr+7
    const int ec  = l & 7;           // expert-group: cols 8ec..8ec+7
    const int bx  = blockIdx.x;
    const int h   = bx & 1;          // K-half
    const int t0  = (bx >> 1) * TOKS;
    const int kb  = h * KBLK + wv * KPW;

    // staging: 4 instrs per tile; instr r covers rows 16r..16r+15, lane l ->
    // row 16r+(l>>2), 16B granule (l&3). Global source pre-swizzled by
    // (row>>3)&3 so the linear LDS dest is read-conflict-light (R5/R6-verified).
    const int srow = l >> 2;
    const int schk = l & 3;
    const float* Xg[4]; const float* Wg[4];
#pragma unroll
    for (int r = 0; r < 4; ++r) {
        const int row  = 16 * r + srow;
        const int koff = ((schk ^ ((row >> 3) & 3)) << 2);
        Xg[r] = X + (size_t)(t0 + row) * HIDDEN + kb + koff;
        Wg[r] = W + (size_t)row * HIDDEN + kb + koff;
    }
    float* wb = smem + wv * WV_FL;   // [X 1024 fl | W 1024 fl]

    float acc[8][8];
#pragma unroll
    for (int i = 0; i < 8; ++i)
#pragma unroll
        for (int j = 0; j < 8; ++j) acc[i][j] = 0.0f;

    const int mtr = (tr & 3) << 2;   // X read swizzle offset (lane-const)
    const int mec = (ec & 3) << 2;   // W read swizzle offset (lane-const)

    // prologue: stage chunk 0
#pragma unroll
    for (int r = 0; r < 4; ++r) gload_lds16(Xg[r], wb + r * 256);
#pragma unroll
    for (int r = 0; r < 4; ++r) gload_lds16(Wg[r], wb + XW_FL + r * 256);

#pragma unroll 1
    for (int c = 0; c < NCH; ++c) {
        asm volatile("s_waitcnt vmcnt(0)" ::: "memory");   // my 8 loads landed
        const float* xl = wb;
        const float* wl = wb + XW_FL;
#pragma unroll
        for (int kg = 0; kg < 4; ++kg) {
            const int kxo = (kg << 2) ^ mtr;
            const int kwo = (kg << 2) ^ mec;
            float4 xfv[8];
#pragma unroll
            for (int i = 0; i < 8; ++i)
                xfv[i] = *(const float4*)(xl + (8 * tr + i) * KC + kxo);
#pragma unroll
            for (int j = 0; j < 8; ++j) {
                const float4 wf = *(const float4*)(wl + (8 * ec + j) * KC + kwo);
#pragma unroll
                for (int i = 0; i < 8; ++i) {
                    acc[i][j] = fmaf(xfv[i].x, wf.x, acc[i][j]);
                    acc[i][j] = fmaf(xfv[i].y, wf.y, acc[i][j]);
                    acc[i][j] = fmaf(xfv[i].z, wf.z, acc[i][j]);
                    acc[i][j] = fmaf(xfv[i].w, wf.w, acc[i][j]);
                }
            }
        }
        asm volatile("s_waitcnt lgkmcnt(0)" ::: "memory");  // LDS reads retired
        if (c + 1 < NCH) {           // WAR-safe: reads done; issue next chunk
            const int ko = (c + 1) * KC;
#pragma unroll
            for (int r = 0; r < 4; ++r) gload_lds16(Xg[r] + ko, wb + r * 256);
#pragma unroll
            for (int r = 0; r < 4; ++r) gload_lds16(Wg[r] + ko, wb + XW_FL + r * 256);
        }
    }

    // ---- cross-wave K-reduction: 3 rounds of pairwise LDS adds.
    // Tile t at smem+t*4096 (16KB); granule index (2ec+g)^tr spreads banks
    // (R6 correctness-verified).
    __syncthreads();
#pragma unroll
    for (int half = 4; half >= 1; half >>= 1) {
        if (wv >= half && wv < 2 * half) {
            float* tb = &smem[(wv - half) * 4096];
#pragma unroll
            for (int i = 0; i < 8; ++i) {
                const int base = (8 * tr + i) * 64;
                *(float4*)&tb[base + (((2 * ec + 0) ^ tr) << 2)] =
                    make_float4(acc[i][0], acc[i][1], acc[i][2], acc[i][3]);
                *(float4*)&tb[base + (((2 * ec + 1) ^ tr) << 2)] =
                    make_float4(acc[i][4], acc[i][5], acc[i][6], acc[i][7]);
            }
        }
        __syncthreads();
        if (wv < half) {
            float* tb = &smem[wv * 4096];
#pragma unroll
            for (int i = 0; i < 8; ++i) {
                const int base = (8 * tr + i) * 64;
                const float4 a = *(const float4*)&tb[base + (((2 * ec + 0) ^ tr) << 2)];
                const float4 b = *(const float4*)&tb[base + (((2 * ec + 1) ^ tr) << 2)];
                acc[i][0] += a.x; acc[i][1] += a.y; acc[i][2] += a.z; acc[i][3] += a.w;
                acc[i][4] += b.x; acc[i][5] += b.y; acc[i][6] += b.z; acc[i][7] += b.w;
            }
        }
        __syncthreads();
    }

    // ---- wave 0 stores the raw 64x64 partial (no bias; combine adds it)
    if (wv == 0) {
        float* dst = (h ? wsP : outLog) + (size_t)t0 * NEXP;
#pragma unroll
        for (int i = 0; i < 8; ++i) {
            float* rowp = dst + (size_t)(8 * tr + i) * NEXP + 8 * ec;
            *(float4*)rowp       = make_float4(acc[i][0], acc[i][1], acc[i][2], acc[i][3]);
            *(float4*)(rowp + 4) = make_float4(acc[i][4], acc[i][5], acc[i][6], acc[i][7]);
        }
    }
}

// Combine: logits = partial0 (in logits region) + partial1 (ws) + bias;
// then top-2 + softmax (R1-verified serial scan, strict > keeps lowest
// index on ties = jax.lax.top_k semantics).
__global__ __launch_bounds__(256) void combine_kernel(
    const float* __restrict__ wsP,
    const float* __restrict__ Bv,
    float* __restrict__ out, int nTok)
{
    __shared__ float tt[64 * 65];
    const int tid = threadIdx.x;
    const int t0  = blockIdx.x * TOKS;
    const size_t offSel = (size_t)nTok * 2;
    const size_t offLog = (size_t)nTok * 4;
    float*       L = out + offLog + (size_t)t0 * NEXP;
    const float* P = wsP + (size_t)t0 * NEXP;

#pragma unroll
    for (int r = 0; r < 4; ++r) {
        const int idx = r * 256 + tid;        // 0..1023 float4-chunks
        const int tok = idx >> 4;
        const int e4  = (idx & 15) * 4;
        const float4 a  = *(const float4*)(L + tok * NEXP + e4);
        const float4 b  = *(const float4*)(P + tok * NEXP + e4);
        const float4 bb = *(const float4*)(Bv + e4);
        const float4 s = make_float4(a.x + b.x + bb.x, a.y + b.y + bb.y,
                                     a.z + b.z + bb.z, a.w + b.w + bb.w);
        *(float4*)(L + tok * NEXP + e4) = s;
        tt[(e4 + 0) * 65 + tok] = s.x;
        tt[(e4 + 1) * 65 + tok] = s.y;
        tt[(e4 + 2) * 65 + tok] = s.z;
        tt[(e4 + 3) * 65 + tok] = s.w;
    }
    __syncthreads();

    if (tid < 64) {
        const int t = tid;
        float m1 = -INFINITY, m2 = -INFINITY;
        int i1 = 0, i2 = 0;
#pragma unroll
        for (int e = 0; e < NEXP; ++e) {
            const float v = tt[e * 65 + t];
            if (v > m1)      { m2 = m1; i2 = i1; m1 = v; i1 = e; }
            else if (v > m2) { m2 = v; i2 = e; }
        }
        const float ex  = expf(m2 - m1);
        const float inv = 1.0f / (1.0f + ex);
        *(float2*)(out + (size_t)(t0 + t) * 2)          = make_float2(inv, ex * inv);
        *(float2*)(out + offSel + (size_t)(t0 + t) * 2) = make_float2((float)i1, (float)i2);
    }

    if (blockIdx.x == 0 && tid == 0)
        out[offLog + (size_t)nTok * NEXP] = 0.0f;   // aux_loss
}

extern "C" void kernel_launch(void* const* d_in, const int* in_sizes, int n_in,
                              void* d_out, int out_size, void* d_ws, size_t ws_size,
                              hipStream_t stream)
{
    const float* X  = (const float*)d_in[0];
    const float* W  = (const float*)d_in[1];
    const float* Bv = (const float*)d_in[2];
    float* out = (float*)d_out;
    const int nTok   = in_sizes[0] / HIDDEN;   // 16384
    const int tiles  = nTok / TOKS;            // 256
    float* outLog = out + (size_t)nTok * 4;
    float* wsP    = (float*)d_ws;              // needs nTok*64*4 = 4.2 MB

    gemm_half_kernel<<<2 * tiles, 512, 0, stream>>>(X, W, outLog, wsP, nTok);
    combine_kernel<<<tiles, 256, 0, stream>>>(wsP, Bv, out, nTok);
}

// Round 8
// 105.729 us; speedup vs baseline: 26.0954x; 8.7326x over previous
//
#include <hip/hip_runtime.h>
#include <math.h>
#include <stdint.h>

#define HIDDEN 4096
#define NEXP   64
#define TOKS   64                 // tokens per main block
#define NKH    4                  // K-splits per block (one per wave quartet)
#define KPH    (HIDDEN / NKH)     // 1024 k per wave
#define NS     (KPH / 32)         // 32 k-steps of 32

typedef __bf16 bf16x8 __attribute__((ext_vector_type(8)));
typedef float  f32x4  __attribute__((ext_vector_type(4)));

union BfU { uint4 u; bf16x8 b; };

// fp32 -> (hi, lo) bf16 split. h = RNE(x); r = x - f32(h) is exact
// (Sterbenz); lo = RNE(r). Dropped lo*lo term ~2^-18 relative.
static __device__ __forceinline__ void cvt_hilo(const float* x8, bf16x8& hi, bf16x8& lo) {
#pragma unroll
    for (int j = 0; j < 8; ++j) {
        const float x = x8[j];
        const __bf16 h = (__bf16)x;
        const float  r = x - (float)h;
        hi[j] = h;
        lo[j] = (__bf16)r;
    }
}

// ---- pre-kernel: W[64][4096] fp32 -> B-fragment-ordered bf16 hi/lo planes.
// Fragment F = S*4 + e (S = k-step 0..127, e = expert-tile 0..3): lane l
// supplies B[col 16e+(l&15)][k 32S+8*(l>>4)+j], j=0..7, stored at
// ws[F*512 + l*8]. Main kernel then loads frags as coalesced dwordx4.
__global__ __launch_bounds__(512) void wconv_kernel(
    const float* __restrict__ W, ushort* __restrict__ wsHi, ushort* __restrict__ wsLo)
{
    const int gid = blockIdx.x * 512 + threadIdx.x;   // 0..32767
    const int S = gid >> 8;
    const int e = (gid >> 6) & 3;
    const int l = gid & 63;
    const int row = 16 * e + (l & 15);
    const int k0  = 32 * S + 8 * (l >> 4);
    const float* src = W + (size_t)row * HIDDEN + k0;
    float x8[8];
    *(float4*)&x8[0] = *(const float4*)src;
    *(float4*)&x8[4] = *(const float4*)(src + 4);
    BfU hi, lo;
    cvt_hilo(x8, hi.b, lo.b);
    const size_t o = ((size_t)(S * 4 + e) * 64 + l) * 8;
    *(uint4*)(wsHi + o) = hi.u;
    *(uint4*)(wsLo + o) = lo.u;
}

// ---- main: bf16x3-split MFMA router. 256 blocks x 1024 thr (16 waves =
// 4 token-groups x 4 K-splits). Wave: 16 tok x 64 exp x K=1024. Per k-step:
// 2 coalesced X dwordx4 (HBM stream), 8 B-frag dwordx4 (L2-resident ws),
// cvt to hi/lo, 12 mfma_f32_16x16x32_bf16 into f32x4 acc[4] (16 VGPR).
// A/B-B share CDNA's symmetric k-slot map => k-permutation cancels; C/D
// layout col=lane&15,row=4*(l>>4)+reg (m89-verified).
__global__ __launch_bounds__(1024, 1) void router_mfma_kernel(
    const float* __restrict__ X,
    const ushort* __restrict__ wsHi, const ushort* __restrict__ wsLo,
    const float* __restrict__ Bv, float* __restrict__ out, int nTok)
{
    __shared__ float tiles[NKH][64][68];   // 69632 B partial tiles
    __shared__ float tt[64 * 65];          // 16640 B transposed logits

    const int tid = threadIdx.x;
    const int wv  = tid >> 6;
    const int tg  = wv >> 2;        // token-group 0..3
    const int kh  = wv & 3;         // K-split 0..3
    const int l   = tid & 63;
    const int g   = l >> 4;         // k-slot group
    const int cr  = l & 15;         // A row / B col within tile
    const int t0  = blockIdx.x * TOKS;

    const float*  xp  = X + (size_t)(t0 + 16 * tg + cr) * HIDDEN + kh * KPH + 8 * g;
    const ushort* whp = wsHi + (size_t)kh * 65536 + (size_t)l * 8;
    const ushort* wlp = wsLo + (size_t)kh * 65536 + (size_t)l * 8;

    f32x4 acc[4] = {{0.f,0.f,0.f,0.f},{0.f,0.f,0.f,0.f},{0.f,0.f,0.f,0.f},{0.f,0.f,0.f,0.f}};

    // double-buffered registers (A/B), all statically indexed (rule #20)
    float4 xA0, xA1, xB0, xB1;
    uint4  whA[4], wlA[4], whB[4], wlB[4];

    // prologue: k-step 0 -> buffer A
    xA0 = *(const float4*)xp;
    xA1 = *(const float4*)(xp + 4);
#pragma unroll
    for (int e = 0; e < 4; ++e) {
        whA[e] = *(const uint4*)(whp + e * 512);
        wlA[e] = *(const uint4*)(wlp + e * 512);
    }

#pragma unroll 1
    for (int s = 0; s < NS; s += 2) {
        // issue k-step s+1 -> buffer B (always valid: NS even)
        {
            const float*  xn = xp + (s + 1) * 32;
            const ushort* wn = whp + (size_t)(s + 1) * 2048;
            const ushort* vn = wlp + (size_t)(s + 1) * 2048;
            xB0 = *(const float4*)xn;
            xB1 = *(const float4*)(xn + 4);
#pragma unroll
            for (int e = 0; e < 4; ++e) {
                whB[e] = *(const uint4*)(wn + e * 512);
                wlB[e] = *(const uint4*)(vn + e * 512);
            }
        }
        // compute k-step s from buffer A
        {
            float x8[8];
            *(float4*)&x8[0] = xA0; *(float4*)&x8[4] = xA1;
            bf16x8 xhi, xlo; cvt_hilo(x8, xhi, xlo);
#pragma unroll
            for (int e = 0; e < 4; ++e) {
                BfU bh, bl; bh.u = whA[e]; bl.u = wlA[e];
                acc[e] = __builtin_amdgcn_mfma_f32_16x16x32_bf16(xhi, bh.b, acc[e], 0, 0, 0);
                acc[e] = __builtin_amdgcn_mfma_f32_16x16x32_bf16(xlo, bh.b, acc[e], 0, 0, 0);
                acc[e] = __builtin_amdgcn_mfma_f32_16x16x32_bf16(xhi, bl.b, acc[e], 0, 0, 0);
            }
        }
        // issue k-step s+2 -> buffer A
        if (s + 2 < NS) {
            const float*  xn = xp + (s + 2) * 32;
            const ushort* wn = whp + (size_t)(s + 2) * 2048;
            const ushort* vn = wlp + (size_t)(s + 2) * 2048;
            xA0 = *(const float4*)xn;
            xA1 = *(const float4*)(xn + 4);
#pragma unroll
            for (int e = 0; e < 4; ++e) {
                whA[e] = *(const uint4*)(wn + e * 512);
                wlA[e] = *(const uint4*)(vn + e * 512);
            }
        }
        // compute k-step s+1 from buffer B
        {
            float x8[8];
            *(float4*)&x8[0] = xB0; *(float4*)&x8[4] = xB1;
            bf16x8 xhi, xlo; cvt_hilo(x8, xhi, xlo);
#pragma unroll
            for (int e = 0; e < 4; ++e) {
                BfU bh, bl; bh.u = whB[e]; bl.u = wlB[e];
                acc[e] = __builtin_amdgcn_mfma_f32_16x16x32_bf16(xhi, bh.b, acc[e], 0, 0, 0);
                acc[e] = __builtin_amdgcn_mfma_f32_16x16x32_bf16(xlo, bh.b, acc[e], 0, 0, 0);
                acc[e] = __builtin_amdgcn_mfma_f32_16x16x32_bf16(xhi, bl.b, acc[e], 0, 0, 0);
            }
        }
    }

    // ---- K-split partials -> LDS tiles. C/D: row = 16tg + 4g + i, col = 16e + cr.
#pragma unroll
    for (int e = 0; e < 4; ++e)
#pragma unroll
        for (int i = 0; i < 4; ++i)
            tiles[kh][16 * tg + 4 * g + i][16 * e + cr] = acc[e][i];
    __syncthreads();

    const size_t offSel = (size_t)nTok * 2;
    const size_t offLog = (size_t)nTok * 4;

    // combine 4 partials + bias; store logits; build transposed tile
    {
        const int tok = tid >> 4;          // 0..63
        const int e4  = (tid & 15) * 4;
        const float4 s0 = *(const float4*)&tiles[0][tok][e4];
        const float4 s1 = *(const float4*)&tiles[1][tok][e4];
        const float4 s2 = *(const float4*)&tiles[2][tok][e4];
        const float4 s3 = *(const float4*)&tiles[3][tok][e4];
        const float4 bb = *(const float4*)(Bv + e4);
        const float4 r = make_float4(s0.x + s1.x + s2.x + s3.x + bb.x,
                                     s0.y + s1.y + s2.y + s3.y + bb.y,
                                     s0.z + s1.z + s2.z + s3.z + bb.z,
                                     s0.w + s1.w + s2.w + s3.w + bb.w);
        *(float4*)(out + offLog + (size_t)(t0 + tok) * NEXP + e4) = r;
        tt[(e4 + 0) * 65 + tok] = r.x;
        tt[(e4 + 1) * 65 + tok] = r.y;
        tt[(e4 + 2) * 65 + tok] = r.z;
        tt[(e4 + 3) * 65 + tok] = r.w;
    }
    __syncthreads();

    // top-2 + softmax (R1/R7-verified): strict > keeps lowest index on ties
    if (tid < 64) {
        const int t = tid;
        float m1 = -INFINITY, m2 = -INFINITY;
        int i1 = 0, i2 = 0;
#pragma unroll
        for (int e = 0; e < NEXP; ++e) {
            const float v = tt[e * 65 + t];
            if (v > m1)      { m2 = m1; i2 = i1; m1 = v; i1 = e; }
            else if (v > m2) { m2 = v; i2 = e; }
        }
        const float ex  = expf(m2 - m1);
        const float inv = 1.0f / (1.0f + ex);
        *(float2*)(out + (size_t)(t0 + t) * 2)          = make_float2(inv, ex * inv);
        *(float2*)(out + offSel + (size_t)(t0 + t) * 2) = make_float2((float)i1, (float)i2);
    }

    if (blockIdx.x == 0 && tid == 0)
        out[offLog + (size_t)nTok * NEXP] = 0.0f;   // aux_loss
}

extern "C" void kernel_launch(void* const* d_in, const int* in_sizes, int n_in,
                              void* d_out, int out_size, void* d_ws, size_t ws_size,
                              hipStream_t stream)
{
    const float* X  = (const float*)d_in[0];
    const float* W  = (const float*)d_in[1];
    const float* Bv = (const float*)d_in[2];
    float* out = (float*)d_out;
    const int nTok = in_sizes[0] / HIDDEN;    // 16384
    ushort* wsHi = (ushort*)d_ws;             // 512 KB
    ushort* wsLo = wsHi + (size_t)NEXP * HIDDEN;  // 512 KB

    wconv_kernel<<<64, 512, 0, stream>>>(W, wsHi, wsLo);
    router_mfma_kernel<<<nTok / TOKS, 1024, 0, stream>>>(X, wsHi, wsLo, Bv, out, nTok);
}

// Round 9
// 86.184 us; speedup vs baseline: 32.0133x; 1.2268x over previous
//
#include <hip/hip_runtime.h>
#include <math.h>
#include <stdint.h>

#define HIDDEN 4096
#define NEXP   64
#define TOKS   64                 // tokens per main block
#define KCH    256                // k floats per staged chunk
#define NCHK   (HIDDEN / KCH)     // 16 chunks
#define CH_FL  (TOKS * KCH)       // 16384 floats per chunk buffer (64KB)

typedef __bf16 bf16x8 __attribute__((ext_vector_type(8)));
typedef float  f32x4  __attribute__((ext_vector_type(4)));

union BfU { uint4 u; bf16x8 b; };

// fp32 -> (hi, lo) bf16 split. h = RNE(x); r = x - f32(h) exact; lo = RNE(r).
// Dropped lo*lo term ~2^-16 relative (R8-verified: absmax identical to fp32).
static __device__ __forceinline__ void cvt_hilo(const float* x8, bf16x8& hi, bf16x8& lo) {
#pragma unroll
    for (int j = 0; j < 8; ++j) {
        const float x = x8[j];
        const __bf16 h = (__bf16)x;
        const float  r = x - (float)h;
        hi[j] = h;
        lo[j] = (__bf16)r;
    }
}

// async global->LDS, 16B/lane, linear dest (wave-uniform base + lane*16)
__device__ __forceinline__ void gload_lds16(const float* g, float* l) {
    __builtin_amdgcn_global_load_lds(
        (const __attribute__((address_space(1))) void*)g,
        (__attribute__((address_space(3))) void*)l, 16, 0, 0);
}

// ---- pre-kernel (R8-verified): W fp32 -> B-fragment-ordered bf16 hi/lo planes.
// Fragment F = S*4 + e (S = global k-step of 32, e = expert-tile): lane l
// supplies B[col 16e+(l&15)][k 32S+8*(l>>4)+j], stored at ws[F*512 + l*8].
__global__ __launch_bounds__(512) void wconv_kernel(
    const float* __restrict__ W, ushort* __restrict__ wsHi, ushort* __restrict__ wsLo)
{
    const int gid = blockIdx.x * 512 + threadIdx.x;   // 0..32767
    const int S = gid >> 8;
    const int e = (gid >> 6) & 3;
    const int l = gid & 63;
    const int row = 16 * e + (l & 15);
    const int k0  = 32 * S + 8 * (l >> 4);
    const float* src = W + (size_t)row * HIDDEN + k0;
    float x8[8];
    *(float4*)&x8[0] = *(const float4*)src;
    *(float4*)&x8[4] = *(const float4*)(src + 4);
    BfU hi, lo;
    cvt_hilo(x8, hi.b, lo.b);
    const size_t o = ((size_t)(S * 4 + e) * 64 + l) * 8;
    *(uint4*)(wsHi + o) = hi.u;
    *(uint4*)(wsLo + o) = lo.u;
}

// ---- main: bf16x3-split MFMA router with LDS-staged, fully-coalesced X.
// 256 blocks x 1024 thr (16 waves = 4 token-groups x 4 K-splits). X staged in
// 64KB chunks (64 tok x 256 k), double-buffered: each global_load_lds covers
// ONE row's contiguous 1KB (perfect coalescing, zero staging VGPRs; R8's
// direct loads were 16-row/16KB-stride scattered -> ~2.6 TB/s only).
// Granule pre-swizzle on the GLOBAL source (mask=row&7, involution, rule #21)
// => fragment-order ds_read_b128 is <=2-way bank conflicts (free). Wave
// (tg,kh): 16 tok x 64 exp, chunk k-slice [kh*64,+64) = 2 MFMA k-steps.
// B-frags from L2-resident ws (R8-verified). One vmcnt(0)+barrier per chunk;
// in-flight 64KB/CU >> BW*latency => HBM stays saturated through the drain.
__global__ __launch_bounds__(1024, 1) void router_mfma_kernel(
    const float* __restrict__ X,
    const ushort* __restrict__ wsHi, const ushort* __restrict__ wsLo,
    const float* __restrict__ Bv, float* __restrict__ out, int nTok)
{
    __shared__ float smem[2 * CH_FL];   // 131072 B; epilogue tiles aliased

    const int tid = threadIdx.x;
    const int wv  = tid >> 6;
    const int tg  = wv >> 2;        // token-group 0..3
    const int kh  = wv & 3;         // K-split 0..3
    const int l   = tid & 63;
    const int g   = l >> 4;         // k-slot group 0..3
    const int cr  = l & 15;         // A row / B col within tile
    const int t0  = blockIdx.x * TOKS;

    // staging: wave wv stages rows 4wv..4wv+3; instr r = one row's 1KB chunk
    // slice, lane i sources global granule (i ^ (row&7)) -> LDS granule i.
    const float* XgS[4];
    int ldst[4];
#pragma unroll
    for (int r = 0; r < 4; ++r) {
        const int row = 4 * wv + r;
        XgS[r] = X + (size_t)(t0 + row) * HIDDEN + ((l ^ (row & 7)) << 2);
        ldst[r] = row * KCH;        // float offset within chunk buffer
    }

    // A-fragment read: row 16tg+cr, granule q_t = kh*16 + 8t + 2g + half,
    // stored at q_t ^ (cr&7). (8t is bit3; mask hits bits0-2 => +32 floats/t.)
    const int m8   = cr & 7;
    const int rowB = (16 * tg + cr) * KCH;
    const int gA0  = (((kh * 16 + 2 * g + 0) ^ m8) << 2);
    const int gA1  = (((kh * 16 + 2 * g + 1) ^ m8) << 2);

    f32x4 acc[4] = {{0.f,0.f,0.f,0.f},{0.f,0.f,0.f,0.f},{0.f,0.f,0.f,0.f},{0.f,0.f,0.f,0.f}};

    // prologue: stage chunk 0 -> buf 0
#pragma unroll
    for (int r = 0; r < 4; ++r) gload_lds16(XgS[r], smem + ldst[r]);

#pragma unroll 1
    for (int c = 0; c < NCHK; ++c) {
        asm volatile("s_waitcnt vmcnt(0)" ::: "memory");   // my chunk-c stages done
        __syncthreads();                                   // all waves' chunk c visible
        const int p = c & 1;
        if (c + 1 < NCHK) {
            float* pb = smem + ((c + 1) & 1) * CH_FL;
            const int ko = (c + 1) * KCH;
#pragma unroll
            for (int r = 0; r < 4; ++r) gload_lds16(XgS[r] + ko, pb + ldst[r]);
        }
        // B-fragments for this chunk (global S = c*8 + kh*2 + t), L2-resident
        const ushort* wh = wsHi + ((size_t)(c * 8 + kh * 2) * 4) * 512 + (size_t)l * 8;
        const ushort* wl = wsLo + ((size_t)(c * 8 + kh * 2) * 4) * 512 + (size_t)l * 8;
        uint4 bh0[4], bl0[4], bh1[4], bl1[4];
#pragma unroll
        for (int e = 0; e < 4; ++e) {
            bh0[e] = *(const uint4*)(wh + e * 512);
            bl0[e] = *(const uint4*)(wl + e * 512);
            bh1[e] = *(const uint4*)(wh + 2048 + e * 512);
            bl1[e] = *(const uint4*)(wl + 2048 + e * 512);
        }
        const float* lb = smem + p * CH_FL + rowB;
        // k-step t=0
        {
            float x8[8];
            *(float4*)&x8[0] = *(const float4*)(lb + gA0);
            *(float4*)&x8[4] = *(const float4*)(lb + gA1);
            bf16x8 xh, xo; cvt_hilo(x8, xh, xo);
#pragma unroll
            for (int e = 0; e < 4; ++e) {
                BfU ph, pl; ph.u = bh0[e]; pl.u = bl0[e];
                acc[e] = __builtin_amdgcn_mfma_f32_16x16x32_bf16(xh, ph.b, acc[e], 0, 0, 0);
                acc[e] = __builtin_amdgcn_mfma_f32_16x16x32_bf16(xo, ph.b, acc[e], 0, 0, 0);
                acc[e] = __builtin_amdgcn_mfma_f32_16x16x32_bf16(xh, pl.b, acc[e], 0, 0, 0);
            }
        }
        // k-step t=1 (+32 floats)
        {
            float x8[8];
            *(float4*)&x8[0] = *(const float4*)(lb + 32 + gA0);
            *(float4*)&x8[4] = *(const float4*)(lb + 32 + gA1);
            bf16x8 xh, xo; cvt_hilo(x8, xh, xo);
#pragma unroll
            for (int e = 0; e < 4; ++e) {
                BfU ph, pl; ph.u = bh1[e]; pl.u = bl1[e];
                acc[e] = __builtin_amdgcn_mfma_f32_16x16x32_bf16(xh, ph.b, acc[e], 0, 0, 0);
                acc[e] = __builtin_amdgcn_mfma_f32_16x16x32_bf16(xo, ph.b, acc[e], 0, 0, 0);
                acc[e] = __builtin_amdgcn_mfma_f32_16x16x32_bf16(xh, pl.b, acc[e], 0, 0, 0);
            }
        }
    }

    __syncthreads();   // all staging reads done before aliasing LDS for tiles

    // ---- epilogue (R8-verified), LDS aliased: tiles 69632B + tt 16640B
    float (*tiles)[64][68] = (float (*)[64][68])smem;
    float* tt = smem + 4 * 64 * 68;

    // C/D layout (m89): row = 16tg + 4g + i, col = 16e + cr
#pragma unroll
    for (int e = 0; e < 4; ++e)
#pragma unroll
        for (int i = 0; i < 4; ++i)
            tiles[kh][16 * tg + 4 * g + i][16 * e + cr] = acc[e][i];
    __syncthreads();

    const size_t offSel = (size_t)nTok * 2;
    const size_t offLog = (size_t)nTok * 4;

    // combine 4 K-split partials + bias; store logits; build transposed tile
    {
        const int tok = tid >> 4;          // 0..63
        const int e4  = (tid & 15) * 4;
        const float4 s0 = *(const float4*)&tiles[0][tok][e4];
        const float4 s1 = *(const float4*)&tiles[1][tok][e4];
        const float4 s2 = *(const float4*)&tiles[2][tok][e4];
        const float4 s3 = *(const float4*)&tiles[3][tok][e4];
        const float4 bb = *(const float4*)(Bv + e4);
        const float4 r = make_float4(s0.x + s1.x + s2.x + s3.x + bb.x,
                                     s0.y + s1.y + s2.y + s3.y + bb.y,
                                     s0.z + s1.z + s2.z + s3.z + bb.z,
                                     s0.w + s1.w + s2.w + s3.w + bb.w);
        *(float4*)(out + offLog + (size_t)(t0 + tok) * NEXP + e4) = r;
        tt[(e4 + 0) * 65 + tok] = r.x;
        tt[(e4 + 1) * 65 + tok] = r.y;
        tt[(e4 + 2) * 65 + tok] = r.z;
        tt[(e4 + 3) * 65 + tok] = r.w;
    }
    __syncthreads();

    // top-2 + softmax (verified): strict > keeps lowest index on ties
    if (tid < 64) {
        const int t = tid;
        float m1 = -INFINITY, m2 = -INFINITY;
        int i1 = 0, i2 = 0;
#pragma unroll
        for (int e = 0; e < NEXP; ++e) {
            const float v = tt[e * 65 + t];
            if (v > m1)      { m2 = m1; i2 = i1; m1 = v; i1 = e; }
            else if (v > m2) { m2 = v; i2 = e; }
        }
        const float ex  = expf(m2 - m1);
        const float inv = 1.0f / (1.0f + ex);
        *(float2*)(out + (size_t)(t0 + t) * 2)          = make_float2(inv, ex * inv);
        *(float2*)(out + offSel + (size_t)(t0 + t) * 2) = make_float2((float)i1, (float)i2);
    }

    if (blockIdx.x == 0 && tid == 0)
        out[offLog + (size_t)nTok * NEXP] = 0.0f;   // aux_loss
}

extern "C" void kernel_launch(void* const* d_in, const int* in_sizes, int n_in,
                              void* d_out, int out_size, void* d_ws, size_t ws_size,
                              hipStream_t stream)
{
    const float* X  = (const float*)d_in[0];
    const float* W  = (const float*)d_in[1];
    const float* Bv = (const float*)d_in[2];
    float* out = (float*)d_out;
    const int nTok = in_sizes[0] / HIDDEN;    // 16384
    ushort* wsHi = (ushort*)d_ws;             // 512 KB
    ushort* wsLo = wsHi + (size_t)NEXP * HIDDEN;  // 512 KB

    wconv_kernel<<<64, 512, 0, stream>>>(W, wsHi, wsLo);
    router_mfma_kernel<<<nTok / TOKS, 1024, 0, stream>>>(X, wsHi, wsLo, Bv, out, nTok);
}

// Round 10
// 70.777 us; speedup vs baseline: 38.9824x; 1.2177x over previous
//
#include <hip/hip_runtime.h>
#include <math.h>
#include <stdint.h>

#define HIDDEN  4096
#define NEXP    64
#define TOKS    64                 // tokens per main block
#define KCH     128                // k floats per staged chunk
#define NCHK    (HIDDEN / KCH)     // 32 chunks
#define XREG_FL (TOKS * KCH)       // 8192 floats: X region (32 KB)
#define PAR_FL  16384              // floats per parity buffer: X 32K | Bhi 16K | Blo 16K

typedef __bf16 bf16x8 __attribute__((ext_vector_type(8)));
typedef float  f32x4  __attribute__((ext_vector_type(4)));

union BfU { uint4 u; bf16x8 b; };

// fp32 -> (hi, lo) bf16 split; dropped lo*lo term ~2^-18 rel (R8/R9-verified).
static __device__ __forceinline__ void cvt_hilo(const float* x8, bf16x8& hi, bf16x8& lo) {
#pragma unroll
    for (int j = 0; j < 8; ++j) {
        const float x = x8[j];
        const __bf16 h = (__bf16)x;
        const float  r = x - (float)h;
        hi[j] = h;
        lo[j] = (__bf16)r;
    }
}

// async global->LDS, 16B/lane, wave-uniform dest base + lane*16
__device__ __forceinline__ void gload_lds16(const void* g, void* l) {
    __builtin_amdgcn_global_load_lds(
        (const __attribute__((address_space(1))) void*)g,
        (__attribute__((address_space(3))) void*)l, 16, 0, 0);
}

// ---- pre-kernel (R8/R9-verified): W fp32 -> B-fragment-ordered bf16 hi/lo.
// Fragment F = S*4 + e (S = k-step of 32): lane l supplies
// B[col 16e+(l&15)][k 32S+8(l>>4)+j] at ws[F*512 + l*8].
__global__ __launch_bounds__(512) void wconv_kernel(
    const float* __restrict__ W, ushort* __restrict__ wsHi, ushort* __restrict__ wsLo)
{
    const int gid = blockIdx.x * 512 + threadIdx.x;   // 0..32767
    const int S = gid >> 8;
    const int e = (gid >> 6) & 3;
    const int l = gid & 63;
    const int row = 16 * e + (l & 15);
    const int k0  = 32 * S + 8 * (l >> 4);
    const float* src = W + (size_t)row * HIDDEN + k0;
    float x8[8];
    *(float4*)&x8[0] = *(const float4*)src;
    *(float4*)&x8[4] = *(const float4*)(src + 4);
    BfU hi, lo;
    cvt_hilo(x8, hi.b, lo.b);
    const size_t o = ((size_t)(S * 4 + e) * 64 + l) * 8;
    *(uint4*)(wsHi + o) = hi.u;
    *(uint4*)(wsLo + o) = lo.u;
}

// ---- main: bf16x3-split MFMA router, X AND B LDS-staged.
// R9 post-mortem: B-frag VGPR loads (issued after staging) serialized on
// vmcnt's in-order retirement, and 4 tg-waves duplicated B reads (4MB/block
// through L1). R10: per 128-k chunk stage X 32KB (coalesced 1KB rows,
// source-granule swizzle mask=row&7 -> b128 reads perfectly banked) + B
// hi/lo 32KB (fragment-ordered = linear source AND linear lane reads).
// Compute touches only LDS => vmcnt(0) paces just the wave's own 4 staging
// loads. B traffic 1MB/block from L2 (was 4MB). One barrier per chunk.
__global__ __launch_bounds__(1024, 1) void router_mfma_kernel(
    const float* __restrict__ X,
    const ushort* __restrict__ wsHi, const ushort* __restrict__ wsLo,
    const float* __restrict__ Bv, float* __restrict__ out, int nTok)
{
    __shared__ float smem[2 * PAR_FL];   // 131072 B; epilogue aliases

    const int tid = threadIdx.x;
    const int wv  = tid >> 6;
    const int tg  = wv >> 2;        // token-group 0..3
    const int kh  = wv & 3;         // K-split 0..3 (k-step within chunk)
    const int l   = tid & 63;
    const int g   = l >> 4;         // k-slot group 0..3
    const int cr  = l & 15;         // A row / B col within tile
    const int t0  = blockIdx.x * TOKS;

    // X staging: 32 instrs, 2 per wave; instr q=2wv+r covers rows 2q,2q+1
    // (512B each). Lane l: row = 2q+(l>>5), granule (l&31)^(row&7).
    const float* XgS[2];
    int xdst[2];
#pragma unroll
    for (int r = 0; r < 2; ++r) {
        const int q   = 2 * wv + r;
        const int row = 2 * q + (l >> 5);
        XgS[r]  = X + (size_t)(t0 + row) * HIDDEN + (((l & 31) ^ (row & 7)) << 2);
        xdst[r] = 2 * q * KCH;      // uniform base; HW adds lane*16B
    }
    // B staging: wave wv stages frag 16c+wv of each plane (1KB linear)
    const ushort* BhS = wsHi + (size_t)wv * 512 + (size_t)l * 8;
    const ushort* BlS = wsLo + (size_t)wv * 512 + (size_t)l * 8;
    const int bhdst = XREG_FL + wv * 256;          // float offsets, uniform
    const int bldst = XREG_FL + 4096 + wv * 256;

    // A-frag read: row 16tg+cr; k-step kh; granule 8kh + ((2g+h)^(cr&7)).
    const int m8   = cr & 7;
    const int rowX = (16 * tg + cr) * KCH;
    const int gA0  = (8 * kh + ((2 * g + 0) ^ m8)) << 2;
    const int gA1  = (8 * kh + ((2 * g + 1) ^ m8)) << 2;

    f32x4 acc[4] = {{0.f,0.f,0.f,0.f},{0.f,0.f,0.f,0.f},{0.f,0.f,0.f,0.f},{0.f,0.f,0.f,0.f}};

    // prologue: stage chunk 0 -> parity 0
#pragma unroll
    for (int r = 0; r < 2; ++r) gload_lds16(XgS[r], smem + xdst[r]);
    gload_lds16(BhS, smem + bhdst);
    gload_lds16(BlS, smem + bldst);

#pragma unroll 1
    for (int c = 0; c < NCHK; ++c) {
        asm volatile("s_waitcnt vmcnt(0)" ::: "memory");   // my 4 stages for c done
        __syncthreads();                                   // chunk c visible to all
        const int p = c & 1;
        if (c + 1 < NCHK) {                                // issue c+1 -> other parity
            float* pb = smem + ((c + 1) & 1) * PAR_FL;
            const int ko = (c + 1) * KCH;
            const size_t bo = (size_t)(c + 1) * 8192;      // 16 frags * 512 ushorts
#pragma unroll
            for (int r = 0; r < 2; ++r) gload_lds16(XgS[r] + ko, pb + xdst[r]);
            gload_lds16(BhS + bo, pb + bhdst);
            gload_lds16(BlS + bo, pb + bldst);
        }
        const float*  xb = smem + p * PAR_FL + rowX;
        const ushort* bh = (const ushort*)(smem + p * PAR_FL + XREG_FL) + (4 * kh) * 512 + l * 8;
        const ushort* bl = bh + 8192;                      // Blo region (+16KB)
        float x8[8];
        *(float4*)&x8[0] = *(const float4*)(xb + gA0);
        *(float4*)&x8[4] = *(const float4*)(xb + gA1);
        bf16x8 xh, xo; cvt_hilo(x8, xh, xo);
#pragma unroll
        for (int e = 0; e < 4; ++e) {
            BfU ph, pl;
            ph.u = *(const uint4*)(bh + e * 512);
            pl.u = *(const uint4*)(bl + e * 512);
            acc[e] = __builtin_amdgcn_mfma_f32_16x16x32_bf16(xh, ph.b, acc[e], 0, 0, 0);
            acc[e] = __builtin_amdgcn_mfma_f32_16x16x32_bf16(xo, ph.b, acc[e], 0, 0, 0);
            acc[e] = __builtin_amdgcn_mfma_f32_16x16x32_bf16(xh, pl.b, acc[e], 0, 0, 0);
        }
    }

    __syncthreads();   // all reads done before aliasing LDS for epilogue

    // ---- epilogue (R8/R9-verified), LDS aliased: tiles 69632B + tt 16640B
    float (*tiles)[64][68] = (float (*)[64][68])smem;
    float* tt = smem + 4 * 64 * 68;

    // C/D layout (m89): row = 16tg + 4g + i, col = 16e + cr
#pragma unroll
    for (int e = 0; e < 4; ++e)
#pragma unroll
        for (int i = 0; i < 4; ++i)
            tiles[kh][16 * tg + 4 * g + i][16 * e + cr] = acc[e][i];
    __syncthreads();

    const size_t offSel = (size_t)nTok * 2;
    const size_t offLog = (size_t)nTok * 4;

    // combine 4 K-split partials + bias; store logits; build transposed tile
    {
        const int tok = tid >> 4;          // 0..63
        const int e4  = (tid & 15) * 4;
        const float4 s0 = *(const float4*)&tiles[0][tok][e4];
        const float4 s1 = *(const float4*)&tiles[1][tok][e4];
        const float4 s2 = *(const float4*)&tiles[2][tok][e4];
        const float4 s3 = *(const float4*)&tiles[3][tok][e4];
        const float4 bb = *(const float4*)(Bv + e4);
        const float4 r = make_float4(s0.x + s1.x + s2.x + s3.x + bb.x,
                                     s0.y + s1.y + s2.y + s3.y + bb.y,
                                     s0.z + s1.z + s2.z + s3.z + bb.z,
                                     s0.w + s1.w + s2.w + s3.w + bb.w);
        *(float4*)(out + offLog + (size_t)(t0 + tok) * NEXP + e4) = r;
        tt[(e4 + 0) * 65 + tok] = r.x;
        tt[(e4 + 1) * 65 + tok] = r.y;
        tt[(e4 + 2) * 65 + tok] = r.z;
        tt[(e4 + 3) * 65 + tok] = r.w;
    }
    __syncthreads();

    // top-2 + softmax (verified): strict > keeps lowest index on ties
    if (tid < 64) {
        const int t = tid;
        float m1 = -INFINITY, m2 = -INFINITY;
        int i1 = 0, i2 = 0;
#pragma unroll
        for (int e = 0; e < NEXP; ++e) {
            const float v = tt[e * 65 + t];
            if (v > m1)      { m2 = m1; i2 = i1; m1 = v; i1 = e; }
            else if (v > m2) { m2 = v; i2 = e; }
        }
        const float ex  = expf(m2 - m1);
        const float inv = 1.0f / (1.0f + ex);
        *(float2*)(out + (size_t)(t0 + t) * 2)          = make_float2(inv, ex * inv);
        *(float2*)(out + offSel + (size_t)(t0 + t) * 2) = make_float2((float)i1, (float)i2);
    }

    if (blockIdx.x == 0 && tid == 0)
        out[offLog + (size_t)nTok * NEXP] = 0.0f;   // aux_loss
}

extern "C" void kernel_launch(void* const* d_in, const int* in_sizes, int n_in,
                              void* d_out, int out_size, void* d_ws, size_t ws_size,
                              hipStream_t stream)
{
    const float* X  = (const float*)d_in[0];
    const float* W  = (const float*)d_in[1];
    const float* Bv = (const float*)d_in[2];
    float* out = (float*)d_out;
    const int nTok = in_sizes[0] / HIDDEN;    // 16384
    ushort* wsHi = (ushort*)d_ws;             // 512 KB
    ushort* wsLo = wsHi + (size_t)NEXP * HIDDEN;  // 512 KB

    wconv_kernel<<<64, 512, 0, stream>>>(W, wsHi, wsLo);
    router_mfma_kernel<<<nTok / TOKS, 1024, 0, stream>>>(X, wsHi, wsLo, Bv, out, nTok);
}